// Round 9
// baseline (144.467 us; speedup 1.0000x reference)
//
#include <hip/hip_runtime.h>
#include <cstdint>

// MultiboxLoss: B=128, P=8732, C=21
//   out[0] = smooth_ex_loss_sum(pos) / n_pos_total
//   out[1] = CE_sum(pos | mined_neg) / n_pos_total
// Hot path: 3*num_pos >= #negatives -> mined set = ALL priors (per-row runtime
// decision; general top-k fallback kept in the fused tail's cold path).
// R9: (a) per-thread MLP forced via volatile inline-asm global_load (compiler
// provably sank C++ loads in R5/R6: VGPR=24/48). All 27 loads for 3 priors
// issued, ONE s_waitcnt vmcnt(0), then pure VALU. (b) single-kernel fusion:
// last-arriving block (ws counter, power-of-2 grid -> poison-proof modulo
// trick) runs the tail; zero extra dispatches, zero memsets.
// Ground truth so far: k_main ~30us @ ~4.4TB/s served (134MB), warm==cold in
// ALL structures -> either per-wave MLP failure or L3-hit BW ceiling. This
// round separates them: VGPR count proves (a) took; timing tells which theory.

#define B_ 128
#define P_ 8732
#define C_ 21
constexpr int TPB = 256;
constexpr int BPR = 16;              // sub-blocks per row
constexpr int GRID = B_ * BPR;       // 2048 (power of 2: required for counter)
constexpr int TPR = BPR * TPB;       // 4096 threads per row
// 3 priors/thread: p0<4096 (always), p1=p0+4096 (always <8732), p2=p0+8192
// (active iff p0<540).

typedef float f4 __attribute__((ext_vector_type(4)));

// volatile asm loads: unsinkable, unreorderable among themselves.
#define LD4(d, a, o) asm volatile("global_load_dwordx4 %0, %1, off offset:" #o : "=v"(d) : "v"(a))
#define LDF(d, a, o) asm volatile("global_load_dword %0, %1, off offset:" #o : "=v"(d) : "v"(a))
#define LDI(d, a)    asm volatile("global_load_dword %0, %1, off" : "=v"(d) : "v"(a))

__device__ __forceinline__ float waveSumF(float v) {
#pragma unroll
  for (int o = 32; o; o >>= 1) v += __shfl_down(v, o);
  return v;
}
__device__ __forceinline__ int waveSumI(int v) {
#pragma unroll
  for (int o = 32; o; o >>= 1) v += __shfl_down(v, o);
  return v;
}
__device__ __forceinline__ double waveSumD(double v) {
#pragma unroll
  for (int o = 32; o; o >>= 1) v += __shfl_down(v, o);
  return v;
}

#define SMEX(d) (((d) < 1.f) ? (1.1565176427496657f * ((d) + (__expf(-2.f * (d)) - 1.f) * 0.5f)) \
                             : ((d) - 0.3434823572503343f))

// one prior on named registers; contributions masked by act
__device__ __forceinline__ void prior21v(f4 c0, f4 c1, f4 c2, f4 c3, f4 c4, float c5,
                                         int lab, f4 pr, f4 gv, bool act,
                                         float& sm, float& cp, float& cn, int& np) {
  float m = fmaxf(fmaxf(fmaxf(c0.x, c0.y), fmaxf(c0.z, c0.w)),
                  fmaxf(fmaxf(c1.x, c1.y), fmaxf(c1.z, c1.w)));
  m = fmaxf(m, fmaxf(fmaxf(c2.x, c2.y), fmaxf(c2.z, c2.w)));
  m = fmaxf(m, fmaxf(fmaxf(c3.x, c3.y), fmaxf(c3.z, c3.w)));
  m = fmaxf(m, fmaxf(fmaxf(c4.x, c4.y), fmaxf(c4.z, c4.w)));
  m = fmaxf(m, c5);
  float s = __expf(c0.x - m) + __expf(c0.y - m) + __expf(c0.z - m) + __expf(c0.w - m);
  s += __expf(c1.x - m) + __expf(c1.y - m) + __expf(c1.z - m) + __expf(c1.w - m);
  s += __expf(c2.x - m) + __expf(c2.y - m) + __expf(c2.z - m) + __expf(c2.w - m);
  s += __expf(c3.x - m) + __expf(c3.y - m) + __expf(c3.z - m) + __expf(c3.w - m);
  s += __expf(c4.x - m) + __expf(c4.y - m) + __expf(c4.z - m) + __expf(c4.w - m);
  s += __expf(c5 - m);
  float xl = c0.x;  // conf[lab] via static cndmask chain
  xl = (lab == 1) ? c0.y : xl;  xl = (lab == 2) ? c0.z : xl;
  xl = (lab == 3) ? c0.w : xl;  xl = (lab == 4) ? c1.x : xl;
  xl = (lab == 5) ? c1.y : xl;  xl = (lab == 6) ? c1.z : xl;
  xl = (lab == 7) ? c1.w : xl;  xl = (lab == 8) ? c2.x : xl;
  xl = (lab == 9) ? c2.y : xl;  xl = (lab == 10) ? c2.z : xl;
  xl = (lab == 11) ? c2.w : xl; xl = (lab == 12) ? c3.x : xl;
  xl = (lab == 13) ? c3.y : xl; xl = (lab == 14) ? c3.z : xl;
  xl = (lab == 15) ? c3.w : xl; xl = (lab == 16) ? c4.x : xl;
  xl = (lab == 17) ? c4.y : xl; xl = (lab == 18) ? c4.z : xl;
  xl = (lab == 19) ? c4.w : xl; xl = (lab == 20) ? c5 : xl;
  const float ce = m + __logf(s) - xl;

  float d, smx;
  d = fabsf(pr.x - gv.x); smx = SMEX(d);
  d = fabsf(pr.y - gv.y); smx += SMEX(d);
  d = fabsf(pr.z - gv.z); smx += SMEX(d);
  d = fabsf(pr.w - gv.w); smx += SMEX(d);

  const bool pos = act && (lab > 0);
  sm += pos ? smx : 0.f;
  cp += pos ? ce : 0.f;
  cn += (act && lab == 0) ? ce : 0.f;
  np += pos ? 1 : 0;
}

// general top-k fallback helper (cold path)
__device__ __forceinline__ unsigned keyCE(const float* __restrict__ conf,
                                          const int* __restrict__ labels,
                                          int b, int p, float& ce) {
  const float* row = conf + ((size_t)b * P_ + p) * C_;
  float m = row[0];
  for (int c = 1; c < C_; ++c) m = fmaxf(m, row[c]);
  float s = 0.f;
  for (int c = 0; c < C_; ++c) s += __expf(row[c] - m);
  const float lse = m + __logf(s);
  const int lab = labels[(size_t)b * P_ + p];
  ce = lse - row[lab];
  if (lab > 0) return 0u;  // positives excluded
  unsigned u = __float_as_uint(lse - row[0]);  // bg_loss -> order-preserving key
  u = (u & 0x80000000u) ? ~u : (u | 0x80000000u);
  return u ? u : 1u;
}

union F2U {
  float2 f;
  unsigned long long u;
};

// ---------------- single fused kernel ----------------
__global__ __launch_bounds__(TPB) void k_fused(
    const float* __restrict__ conf, const float* __restrict__ pred,
    const int* __restrict__ labels, const float* __restrict__ gt,
    unsigned long long* __restrict__ slots, unsigned* __restrict__ cnt,
    float* __restrict__ out) {
  const int tid = threadIdx.x;
  const int row = blockIdx.x >> 4;  // BPR = 16
  const int sub = blockIdx.x & 15;
  const int p0 = sub * TPB + tid;   // [0, 4096)
  const int p1 = p0 + TPR;          // always < P_
  const int p2 = p0 + 2 * TPR;
  const bool act2 = p2 < P_;
  const int p2c = act2 ? p2 : p0;   // clamp (contribution masked)
  const size_t rb = (size_t)row * P_;

  // ---- issue ALL 27 loads via volatile asm (cannot be sunk) ----
  const uint64_t ca0 = (uint64_t)(conf + (rb + p0) * C_);
  const uint64_t ca1 = (uint64_t)(conf + (rb + p1) * C_);
  const uint64_t ca2 = (uint64_t)(conf + (rb + (size_t)p2c) * C_);
  const uint64_t la0 = (uint64_t)(labels + rb + p0);
  const uint64_t la1 = (uint64_t)(labels + rb + p1);
  const uint64_t la2 = (uint64_t)(labels + rb + p2c);
  const uint64_t pa0 = (uint64_t)(pred + (rb + p0) * 4);
  const uint64_t pa1 = (uint64_t)(pred + (rb + p1) * 4);
  const uint64_t pa2 = (uint64_t)(pred + (rb + (size_t)p2c) * 4);
  const uint64_t ga0 = (uint64_t)(gt + (rb + p0) * 4);
  const uint64_t ga1 = (uint64_t)(gt + (rb + p1) * 4);
  const uint64_t ga2 = (uint64_t)(gt + (rb + (size_t)p2c) * 4);

  f4 A0, A1, A2, A3, A4, B0, B1, B2, B3, B4, C0, C1, C2, C3, C4;
  float A5, B5, C5;
  int LA, LB, LC;
  f4 PA, PB, PC, GA, GB, GC;
  LD4(A0, ca0, 0); LD4(A1, ca0, 16); LD4(A2, ca0, 32); LD4(A3, ca0, 48); LD4(A4, ca0, 64); LDF(A5, ca0, 80);
  LD4(B0, ca1, 0); LD4(B1, ca1, 16); LD4(B2, ca1, 32); LD4(B3, ca1, 48); LD4(B4, ca1, 64); LDF(B5, ca1, 80);
  LD4(C0, ca2, 0); LD4(C1, ca2, 16); LD4(C2, ca2, 32); LD4(C3, ca2, 48); LD4(C4, ca2, 64); LDF(C5, ca2, 80);
  LDI(LA, la0); LDI(LB, la1); LDI(LC, la2);
  LD4(PA, pa0, 0); LD4(PB, pa1, 0); LD4(PC, pa2, 0);
  LD4(GA, ga0, 0); LD4(GB, ga1, 0); LD4(GC, ga2, 0);

  asm volatile("s_waitcnt vmcnt(0)" ::: "memory");
  __builtin_amdgcn_sched_barrier(0);

  // ---- pure VALU ----
  float sm = 0.f, cp = 0.f, cn = 0.f;
  int np = 0;
  prior21v(A0, A1, A2, A3, A4, A5, LA, PA, GA, true, sm, cp, cn, np);
  prior21v(B0, B1, B2, B3, B4, B5, LB, PB, GB, true, sm, cp, cn, np);
  prior21v(C0, C1, C2, C3, C4, C5, LC, PC, GC, act2, sm, cp, cn, np);

  // ---- block reduction ----
  const float r0 = waveSumF(sm), r1 = waveSumF(cp), r2 = waveSumF(cn);
  const int r3 = waveSumI(np);
  __shared__ float s0[4], s1[4], s2[4];
  __shared__ int s3[4];
  __shared__ int s_win;
  const int wid = tid >> 6, lane = tid & 63;
  if (lane == 0) { s0[wid] = r0; s1[wid] = r1; s2[wid] = r2; s3[wid] = r3; }
  __syncthreads();
  if (tid == 0) {
    F2U w0, w1;
    w0.f = make_float2(s0[0] + s0[1] + s0[2] + s0[3], s1[0] + s1[1] + s1[2] + s1[3]);
    w1.f = make_float2(s2[0] + s2[1] + s2[2] + s2[3], (float)(s3[0] + s3[1] + s3[2] + s3[3]));
    __hip_atomic_store(&slots[2 * blockIdx.x], w0.u, __ATOMIC_RELAXED, __HIP_MEMORY_SCOPE_AGENT);
    __hip_atomic_store(&slots[2 * blockIdx.x + 1], w1.u, __ATOMIC_RELAXED, __HIP_MEMORY_SCOPE_AGENT);
    __threadfence();
    const unsigned old = __hip_atomic_fetch_add(cnt, 1u, __ATOMIC_ACQ_REL, __HIP_MEMORY_SCOPE_AGENT);
    // exactly one block per call satisfies this for ANY initial counter value
    s_win = ((old & (GRID - 1)) == (GRID - 1)) ? 1 : 0;
  }
  __syncthreads();
  if (!s_win) return;

  // ================= fused tail (runs in the last-arriving block) ==========
  __threadfence();
  __shared__ int s_np[B_], s_flag[B_];
  __shared__ double sdA[4], sdB[4], sdC[4];
  __shared__ int siN[4];
  __shared__ double s_extra;
  __shared__ int icnt[4];
  __shared__ float fsum[4];

  // per-row gather: thread t < 128 sums row t's 16 slots (fixed order)
  double smR = 0.0, cpR = 0.0, cnSel = 0.0;
  int npR = 0;
  if (tid < B_) {
    double cnR = 0.0;
#pragma unroll
    for (int i = 0; i < BPR; ++i) {
      const int sidx = tid * BPR + i;
      F2U a, b;
      a.u = __hip_atomic_load(&slots[2 * sidx], __ATOMIC_RELAXED, __HIP_MEMORY_SCOPE_AGENT);
      b.u = __hip_atomic_load(&slots[2 * sidx + 1], __ATOMIC_RELAXED, __HIP_MEMORY_SCOPE_AGENT);
      smR += (double)a.f.x;
      cpR += (double)a.f.y;
      cnR += (double)b.f.x;
      npR += (int)b.f.y;
    }
    s_np[tid] = npR;
    const int fl = (3 * npR < P_ - npR) ? 1 : 0;  // hot: all negs mined -> 0
    s_flag[tid] = fl;
    if (!fl) cnSel = cnR;
  }
  const double t1 = waveSumD(smR), t2 = waveSumD(cpR), t3 = waveSumD(cnSel);
  const int t4 = waveSumI(npR);
  if (lane == 0) { sdA[wid] = t1; sdB[wid] = t2; sdC[wid] = t3; siN[wid] = t4; }
  if (tid == 0) s_extra = 0.0;
  __syncthreads();

  // cold path: general top-k fallback (never taken for this data)
  for (int b = 0; b < B_; ++b) {
    if (!s_flag[b]) continue;  // uniform (LDS)
    const int need = 3 * s_np[b];
    unsigned long long lo = 1, hi = 0xFFFFFFFFull, ans = 1;
    while (lo <= hi) {
      const unsigned long long mid = lo + ((hi - lo) >> 1);
      int c = 0;
      float dummy;
      for (int p = tid; p < P_; p += TPB)
        if ((unsigned long long)keyCE(conf, labels, b, p, dummy) >= mid) c++;
      c = waveSumI(c);
      if (lane == 0) icnt[wid] = c;
      __syncthreads();
      const int tot = icnt[0] + icnt[1] + icnt[2] + icnt[3];
      if (tot >= need) { ans = mid; lo = mid + 1; } else { hi = mid - 1; }
      __syncthreads();
    }
    int cgt = 0;
    float sgt = 0.f;
    for (int p = tid; p < P_; p += TPB) {
      float ce;
      const unsigned long long k = keyCE(conf, labels, b, p, ce);
      if (k > ans) { cgt++; sgt += ce; }
    }
    cgt = waveSumI(cgt);
    sgt = waveSumF(sgt);
    if (lane == 0) { icnt[wid] = cgt; fsum[wid] = sgt; }
    __syncthreads();
    if (tid == 0) {
      const int gtot = icnt[0] + icnt[1] + icnt[2] + icnt[3];
      double sx = (double)(fsum[0] + fsum[1] + fsum[2] + fsum[3]);
      int rm = need - gtot;
      int taken = 0;
      for (int p = 0; p < P_ && taken < rm; ++p) {  // stable tie-break by index
        float ce;
        if (keyCE(conf, labels, b, p, ce) == ans) { sx += ce; taken++; }
      }
      s_extra += sx;
    }
    __syncthreads();
  }

  // finalize
  if (tid == 0) {
    const double G0 = sdA[0] + sdA[1] + sdA[2] + sdA[3];
    const double G1 = sdB[0] + sdB[1] + sdB[2] + sdB[3];
    const double G2 = sdC[0] + sdC[1] + sdC[2] + sdC[3] + s_extra;
    const double N = (double)(siN[0] + siN[1] + siN[2] + siN[3]);
    out[0] = (float)(G0 / N);
    out[1] = (float)((G1 + G2) / N);
  }
}

extern "C" void kernel_launch(void* const* d_in, const int* in_sizes, int n_in,
                              void* d_out, int out_size, void* d_ws, size_t ws_size,
                              hipStream_t stream) {
  const float* conf = (const float*)d_in[0];
  const float* pred = (const float*)d_in[1];
  const int* labels = (const int*)d_in[2];
  const float* gt = (const float*)d_in[3];
  float* out = (float*)d_out;

  // ws: slots[2*GRID] u64 (fully rewritten every call) + counter u32
  // (monotonic; the power-of-2 modulo trick works for ANY initial value,
  // including the harness's 0xAA poison -> no memset, no init dependence).
  unsigned long long* slots = (unsigned long long*)d_ws;
  unsigned* cnt = (unsigned*)(slots + 2 * GRID);

  hipLaunchKernelGGL(k_fused, dim3(GRID), dim3(TPB), 0, stream,
                     conf, pred, labels, gt, slots, cnt, out);
}